// Round 3
// baseline (292.131 us; speedup 1.0000x reference)
//
#include <hip/hip_runtime.h>
#include <float.h>
#include <math.h>

#define TOKENS 16384
#define HIDDEN 2048
#define NEXP 128
#define TOPK 8
#define NCAND 12
#define DELTA 5e-4f

#define BM 64
#define BK 64
#define KIT (HIDDEN / BK)   // 32 iterations
#define NBUF 3

typedef float f32x16 __attribute__((ext_vector_type(16)));
typedef short bf16x8 __attribute__((ext_vector_type(8)));

__device__ __forceinline__ unsigned pack_hi(float a, float b) {
    return (__float_as_uint(a) >> 16) | (__float_as_uint(b) & 0xFFFF0000u);
}
__device__ __forceinline__ float resid(float a) {
    return a - __uint_as_float(__float_as_uint(a) & 0xFFFF0000u);
}

__device__ __forceinline__ bf16x8 pack8_hi(const float4 a, const float4 b) {
    union { uint4 u; bf16x8 v; } t;
    t.u.x = pack_hi(a.x, a.y); t.u.y = pack_hi(a.z, a.w);
    t.u.z = pack_hi(b.x, b.y); t.u.w = pack_hi(b.z, b.w);
    return t.v;
}
__device__ __forceinline__ bf16x8 pack8_lo(const float4 a, const float4 b) {
    union { uint4 u; bf16x8 v; } t;
    t.u.x = pack_hi(resid(a.x), resid(a.y)); t.u.y = pack_hi(resid(a.z), resid(a.w));
    t.u.z = pack_hi(resid(b.x), resid(b.y)); t.u.w = pack_hi(resid(b.z), resid(b.w));
    return t.v;
}

__device__ __forceinline__ void load_lds_16B(const void* g, void* l) {
    __builtin_amdgcn_global_load_lds(
        (const __attribute__((address_space(1))) unsigned int*)g,
        (__attribute__((address_space(3))) unsigned int*)l, 16, 0, 0);
}

// ---------------------------------------------------------------------------
// K0: pre-split W into 32x32x16-fragment-ordered bf16 hi/lo (verified r6).
// Chunk c = k16*8 + nt*2 + hl; lane l: expert = nt*32+(l&31), k = k16*16+(l>>5)*8+j.
// UNCHANGED.
// ---------------------------------------------------------------------------
__global__ __launch_bounds__(256) void presplit_w(const float* __restrict__ W,
                                                  unsigned short* __restrict__ Ws) {
    const int c = blockIdx.x * 256 + threadIdx.x;   // [0, 65536)
    const int lane = c & 63;
    const int q = c >> 6;
    const int hl = q & 1;
    const int nt = (q >> 1) & 3;
    const int k16 = q >> 3;
    const int e = nt * 32 + (lane & 31);
    const int k0 = k16 * 16 + (lane >> 5) * 8;
    const float* wp = W + (size_t)e * HIDDEN + k0;
    float4 a = *(const float4*)wp;
    float4 b = *(const float4*)(wp + 4);
    if (hl) {
        a.x = resid(a.x); a.y = resid(a.y); a.z = resid(a.z); a.w = resid(a.w);
        b.x = resid(b.x); b.y = resid(b.y); b.z = resid(b.z); b.w = resid(b.w);
    }
    uint4 o;
    o.x = pack_hi(a.x, a.y); o.y = pack_hi(a.z, a.w);
    o.z = pack_hi(b.x, b.y); o.w = pack_hi(b.z, b.w);
    *(uint4*)(Ws + (size_t)c * 8) = o;
}

// ---------------------------------------------------------------------------
// K1 (v4): BM=64, 512 threads (8 waves = 2 M-halves x 4 expert groups),
// grid 256 = 1 block/CU, TRIPLE-buffered LDS (144 KB), counted vmcnt with
// 2-iteration DMA lookahead.
//  - halves B L2 traffic vs BM=32 (256 blocks x 1 MB) and cuts per-CU
//    inbound staging to 48 KB/iter (was 80).
//  - per wave per iter: 2 A-DMA + 4 B-DMA = 6; vmcnt(12) leaves the two
//    youngest iterations (12 DMAs) in flight, drains the one needed next.
//  - A XOR-swizzled via pre-swizzled global source (rule 21), read 2-way
//    bank-aliased = free. B fragment-ordered, lane-linear.
//  - clamped tail re-issue keeps the vmcnt counting invariant.
//  Accumulation order over (kt, s, 3 split terms) bit-identical to r0/r2.
// ---------------------------------------------------------------------------
__global__ __launch_bounds__(512, 2) void router_gemm(const float* __restrict__ X,
                                                      const unsigned short* __restrict__ Ws,
                                                      float* __restrict__ logits) {
    __shared__ float sA[NBUF][BM * BK];            // 3 x 16 KB
    __shared__ unsigned short sB[NBUF][32 * 512];  // 3 x 32 KB  (total 144 KB)

    const int tid = threadIdx.x;
    const int lane = tid & 63;
    const int wid = tid >> 6;        // 0..7
    const int wc = wid & 3;          // expert group (32 experts)
    const int wr = wid >> 2;         // M half (32 tokens)
    const int t0 = blockIdx.x * BM;

    // ---- staging geometry (per wave per iter: 2 A-DMA + 4 B-DMA) ----
    // A instr i (= wid*2 + j) covers rows 4i..4i+3; lane l -> row r = 4i+(l>>4),
    // LDS slot l&15, source k4 = (l&15)^(r&15)  (inverse swizzle on global src).
    const int ai0 = wid * 2, ai1 = wid * 2 + 1;
    const int ar0 = 4 * ai0 + (lane >> 4);
    const int ar1 = 4 * ai1 + (lane >> 4);
    const int ak0 = ((lane & 15) ^ (ar0 & 15)) * 4;
    const int ak1 = ((lane & 15) ^ (ar1 & 15)) * 4;
    const float* aSrc0 = X + (size_t)(t0 + ar0) * HIDDEN + ak0;
    const float* aSrc1 = X + (size_t)(t0 + ar1) * HIDDEN + ak1;
    // B: wave w stages local chunks w*4..w*4+3 of the iteration's 32-chunk slab.
    const unsigned short* bSrc = Ws + ((size_t)wid * 4) * 512 + (size_t)lane * 8;

    // ---- compute geometry ----
    const int cr = wr * 32 + (lane & 31);          // A row in tile
    const int kb = (lane >> 5) * 2;
    int aoff[4][2];
#pragma unroll
    for (int s = 0; s < 4; ++s) {
        aoff[s][0] = cr * 64 + (((s * 4 + kb + 0) ^ (cr & 15)) * 4);
        aoff[s][1] = cr * 64 + (((s * 4 + kb + 1) ^ (cr & 15)) * 4);
    }
    const int boff = (wc * 2) * 512 + lane * 8;

    f32x16 acc;
#pragma unroll
    for (int r = 0; r < 16; ++r) acc[r] = 0.f;

    // ---- prologue: stage iters 0,1,2 into bufs 0,1,2 (18 DMAs/wave) ----
#pragma unroll
    for (int kt = 0; kt < NBUF; ++kt) {
        load_lds_16B(aSrc0 + kt * BK, &sA[kt][ai0 * 256]);
        load_lds_16B(aSrc1 + kt * BK, &sA[kt][ai1 * 256]);
#pragma unroll
        for (int i = 0; i < 4; ++i)
            load_lds_16B(bSrc + ((size_t)kt * 32 + i) * 512, &sB[kt][(wid * 4 + i) * 512]);
    }
    asm volatile("s_waitcnt vmcnt(12)" ::: "memory");   // iter 0 landed (1,2 in flight)
    __builtin_amdgcn_s_barrier();
    asm volatile("" ::: "memory");

    int cur = 0;
#pragma unroll 1
    for (int kt = 0; kt < KIT; ++kt) {
        const float* aBuf = &sA[cur][0];
        const unsigned short* bBuf = &sB[cur][0];

        // ---- compute current buffer: 4 k16-steps x 3 split-terms ----
#pragma unroll
        for (int s = 0; s < 4; ++s) {
            const float4 f0 = *(const float4*)(aBuf + aoff[s][0]);
            const float4 f1 = *(const float4*)(aBuf + aoff[s][1]);
            const bf16x8 ah = pack8_hi(f0, f1);
            const bf16x8 al = pack8_lo(f0, f1);
            const bf16x8 bh = *(const bf16x8*)(bBuf + boff + s * 4096);
            const bf16x8 bl = *(const bf16x8*)(bBuf + boff + s * 4096 + 512);
            acc = __builtin_amdgcn_mfma_f32_32x32x16_bf16(ah, bh, acc, 0, 0, 0);
            acc = __builtin_amdgcn_mfma_f32_32x32x16_bf16(ah, bl, acc, 0, 0, 0);
            acc = __builtin_amdgcn_mfma_f32_32x32x16_bf16(al, bh, acc, 0, 0, 0);
        }

        __builtin_amdgcn_s_barrier();      // all waves done READING buf[cur]
        asm volatile("" ::: "memory");

        // ---- stage iter kt+3 into buf[cur] ((kt+3)%3 == kt%3); clamped tail
        // re-issue keeps the outstanding-DMA count topology for vmcnt(12).
        int kn = kt + 3; if (kn > KIT - 1) kn = KIT - 1;
        load_lds_16B(aSrc0 + kn * BK, &sA[cur][ai0 * 256]);
        load_lds_16B(aSrc1 + kn * BK, &sA[cur][ai1 * 256]);
#pragma unroll
        for (int i = 0; i < 4; ++i)
            load_lds_16B(bSrc + ((size_t)kn * 32 + i) * 512, &sB[cur][(wid * 4 + i) * 512]);

        // counted wait: batch kt+1 (issued 2 iters ago) drained; batches
        // kt+2 and kt+3 (12 DMAs) stay in flight across the barrier.
        asm volatile("s_waitcnt vmcnt(12)" ::: "memory");
        __builtin_amdgcn_sched_barrier(0);
        __builtin_amdgcn_s_barrier();      // everyone's kt+1 data visible
        asm volatile("" ::: "memory");

        cur = (cur == NBUF - 1) ? 0 : cur + 1;
    }
    asm volatile("s_waitcnt vmcnt(0)" ::: "memory");    // drain tail DMAs

    // C/D: col=lane&31, row=(reg&3)+8*(reg>>2)+4*(lane>>5)  (r6-verified)
    const int e = wc * 32 + (lane & 31);
    const int rbase = wr * 32 + 4 * (lane >> 5);
#pragma unroll
    for (int reg = 0; reg < 16; ++reg) {
        const int row = (reg & 3) + 8 * (reg >> 2) + rbase;
        logits[(size_t)(t0 + row) * NEXP + e] = acc[reg];
    }
}

// ---------------------------------------------------------------------------
// K2: fused select+refine. UNCHANGED.
// ---------------------------------------------------------------------------
__global__ __launch_bounds__(256) void router_topk(const float* __restrict__ logits,
                                                   const float* __restrict__ X,
                                                   const float* __restrict__ W,
                                                   float* __restrict__ top_vals,
                                                   float* __restrict__ top_idx) {
    const int lane = threadIdx.x & 63;
    const int t = blockIdx.x * 4 + (threadIdx.x >> 6);
    const float* lrow = logits + (size_t)t * NEXP;
    const float l0 = lrow[lane];
    const float l1 = lrow[lane + 64];
    bool r0 = false, r1 = false;
    float vals[NCAND]; int idxs[NCAND];

#pragma unroll
    for (int it = 0; it < TOPK + 1; ++it) {
        const float c0 = r0 ? -FLT_MAX : l0;
        const float c1 = r1 ? -FLT_MAX : l1;
        float v; int id;
        if (c1 > c0) { v = c1; id = lane + 64; }
        else         { v = c0; id = lane; }
#pragma unroll
        for (int off = 1; off < 64; off <<= 1) {
            const float ov = __shfl_xor(v, off);
            const int   oi = __shfl_xor(id, off);
            if (ov > v || (ov == v && oi < id)) { v = ov; id = oi; }
        }
        vals[it] = v; idxs[it] = id;
        if (id == lane) r0 = true;
        else if (id == lane + 64) r1 = true;
    }

    float ming = FLT_MAX;
#pragma unroll
    for (int i = 0; i < TOPK; ++i) ming = fminf(ming, vals[i] - vals[i + 1]);

    if (ming >= DELTA) {
        if (lane == 0) {
            const float m = vals[0];
            float ex[TOPK], s = 0.f;
#pragma unroll
            for (int i = 0; i < TOPK; ++i) { ex[i] = expf(vals[i] - m); s += ex[i]; }
            const float inv = 1.f / s;
#pragma unroll
            for (int i = 0; i < TOPK; ++i) {
                top_vals[(size_t)t * TOPK + i] = ex[i] * inv;
                top_idx[(size_t)t * TOPK + i] = (float)idxs[i];
            }
        }
        return;
    }

    // ---- slow path (wave-uniform): extend candidates to NCAND
#pragma unroll
    for (int it = TOPK + 1; it < NCAND; ++it) {
        const float c0 = r0 ? -FLT_MAX : l0;
        const float c1 = r1 ? -FLT_MAX : l1;
        float v; int id;
        if (c1 > c0) { v = c1; id = lane + 64; }
        else         { v = c0; id = lane; }
#pragma unroll
        for (int off = 1; off < 64; off <<= 1) {
            const float ov = __shfl_xor(v, off);
            const int   oi = __shfl_xor(id, off);
            if (ov > v || (ov == v && oi < id)) { v = ov; id = oi; }
        }
        vals[it] = v; idxs[it] = id;
        if (id == lane) r0 = true;
        else if (id == lane + 64) r1 = true;
    }

    // exact fp64 recompute of the NCAND candidate logits (coalesced)
    const float* xr = X + (size_t)t * HIDDEN;
    double xd[32];
#pragma unroll
    for (int j = 0; j < 8; ++j) {
        const float4 v = *(const float4*)(xr + j * 256 + lane * 4);
        xd[j * 4 + 0] = (double)v.x; xd[j * 4 + 1] = (double)v.y;
        xd[j * 4 + 2] = (double)v.z; xd[j * 4 + 3] = (double)v.w;
    }
    double acc[NCAND];
#pragma unroll
    for (int c = 0; c < NCAND; ++c) {
        const float* wr = W + (size_t)idxs[c] * HIDDEN;
        double a0 = 0.0, a1 = 0.0;
#pragma unroll
        for (int j = 0; j < 8; ++j) {
            const float4 w = *(const float4*)(wr + j * 256 + lane * 4);
            a0 = fma((double)w.x, xd[j * 4 + 0], a0);
            a1 = fma((double)w.y, xd[j * 4 + 1], a1);
            a0 = fma((double)w.z, xd[j * 4 + 2], a0);
            a1 = fma((double)w.w, xd[j * 4 + 3], a1);
        }
        acc[c] = a0 + a1;
    }
#pragma unroll
    for (int c = 0; c < NCAND; ++c)
#pragma unroll
        for (int off = 1; off < 64; off <<= 1)
            acc[c] += __shfl_xor(acc[c], off);

    int rank[NCAND];
#pragma unroll
    for (int c = 0; c < NCAND; ++c) {
        int r = 0;
#pragma unroll
        for (int m = 0; m < NCAND; ++m)
            if (acc[m] > acc[c] || (acc[m] == acc[c] && idxs[m] < idxs[c])) ++r;
        rank[c] = r;
    }
    double vmax = acc[0];
#pragma unroll
    for (int c = 0; c < NCAND; ++c) if (rank[c] == 0) vmax = acc[c];
    float ex[NCAND], s = 0.f;
#pragma unroll
    for (int c = 0; c < NCAND; ++c) {
        ex[c] = (rank[c] < TOPK) ? expf((float)(acc[c] - vmax)) : 0.f;
        s += ex[c];
    }
    const float inv = 1.f / s;
    if (lane == 0) {
#pragma unroll
        for (int c = 0; c < NCAND; ++c)
            if (rank[c] < TOPK) {
                top_vals[(size_t)t * TOPK + rank[c]] = ex[c] * inv;
                top_idx[(size_t)t * TOPK + rank[c]] = (float)idxs[c];
            }
    }
}

extern "C" void kernel_launch(void* const* d_in, const int* in_sizes, int n_in,
                              void* d_out, int out_size, void* d_ws, size_t ws_size,
                              hipStream_t stream) {
    const float* X = (const float*)d_in[0];   // [16384, 2048] f32
    const float* W = (const float*)d_in[1];   // [128, 2048] f32
    float* logits = (float*)d_out;                          // [16384,128]
    float* tvals  = logits + (size_t)TOKENS * NEXP;         // [16384,8]
    float* tidx   = tvals + (size_t)TOKENS * TOPK;          // [16384,8]

    unsigned short* Wsplit = (unsigned short*)d_ws;         // 1 MB

    presplit_w<<<256, 256, 0, stream>>>(W, Wsplit);
    router_gemm<<<TOKENS / BM, 512, 0, stream>>>(X, Wsplit, logits);
    router_topk<<<TOKENS / 4, 256, 0, stream>>>(logits, X, W, tvals, tidx);
}

// Round 5
// 279.218 us; speedup vs baseline: 1.0462x; 1.0462x over previous
//
#include <hip/hip_runtime.h>
#include <float.h>
#include <math.h>

#define TOKENS 16384
#define HIDDEN 2048
#define NEXP 128
#define TOPK 8
#define NCAND 12
#define DELTA 5e-4f

#define BM 32
#define BK 64
#define KIT (HIDDEN / BK)   // 32 iterations

typedef float f32x16 __attribute__((ext_vector_type(16)));
typedef short bf16x8 __attribute__((ext_vector_type(8)));

__device__ __forceinline__ unsigned pack_hi(float a, float b) {
    return (__float_as_uint(a) >> 16) | (__float_as_uint(b) & 0xFFFF0000u);
}
__device__ __forceinline__ float resid(float a) {
    return a - __uint_as_float(__float_as_uint(a) & 0xFFFF0000u);
}

__device__ __forceinline__ bf16x8 pack8_hi(const float4 a, const float4 b) {
    union { uint4 u; bf16x8 v; } t;
    t.u.x = pack_hi(a.x, a.y); t.u.y = pack_hi(a.z, a.w);
    t.u.z = pack_hi(b.x, b.y); t.u.w = pack_hi(b.z, b.w);
    return t.v;
}
__device__ __forceinline__ bf16x8 pack8_lo(const float4 a, const float4 b) {
    union { uint4 u; bf16x8 v; } t;
    t.u.x = pack_hi(resid(a.x), resid(a.y)); t.u.y = pack_hi(resid(a.z), resid(a.w));
    t.u.z = pack_hi(resid(b.x), resid(b.y)); t.u.w = pack_hi(resid(b.z), resid(b.w));
    return t.v;
}

__device__ __forceinline__ void load_lds_16B(const void* g, void* l) {
    __builtin_amdgcn_global_load_lds(
        (const __attribute__((address_space(1))) unsigned int*)g,
        (__attribute__((address_space(3))) unsigned int*)l, 16, 0, 0);
}

// ---------------------------------------------------------------------------
// K0: pre-split W into 32x32x16-fragment-ordered bf16 hi/lo (verified r6).
// Chunk c = k16*8 + nt*2 + hl; lane l: expert = nt*32+(l&31), k = k16*16+(l>>5)*8+j.
// UNCHANGED.
// ---------------------------------------------------------------------------
__global__ __launch_bounds__(256) void presplit_w(const float* __restrict__ W,
                                                  unsigned short* __restrict__ Ws) {
    const int c = blockIdx.x * 256 + threadIdx.x;   // [0, 65536)
    const int lane = c & 63;
    const int q = c >> 6;
    const int hl = q & 1;
    const int nt = (q >> 1) & 3;
    const int k16 = q >> 3;
    const int e = nt * 32 + (lane & 31);
    const int k0 = k16 * 16 + (lane >> 5) * 8;
    const float* wp = W + (size_t)e * HIDDEN + k0;
    float4 a = *(const float4*)wp;
    float4 b = *(const float4*)(wp + 4);
    if (hl) {
        a.x = resid(a.x); a.y = resid(a.y); a.z = resid(a.z); a.w = resid(a.w);
        b.x = resid(b.x); b.y = resid(b.y); b.z = resid(b.z); b.w = resid(b.w);
    }
    uint4 o;
    o.x = pack_hi(a.x, a.y); o.y = pack_hi(a.z, a.w);
    o.z = pack_hi(b.x, b.y); o.w = pack_hi(b.z, b.w);
    *(uint4*)(Ws + (size_t)c * 8) = o;
}

// ---------------------------------------------------------------------------
// K1 (v5, resubmitted after infra failure — unchanged):
//  - A: DMA-staged f32 [32][64] double-buffer (2 x 8 KB LDS only), XOR
//    swizzle via pre-swizzled global source (rule 21), read 2-way = free.
//  - B: fragment-ordered Ws chunks loaded DIRECTLY to VGPRs (lane-linear
//    16 B/lane, coalesced, L2-hot), 2 iterations deep in named register
//    stages (period-2 unrolled loop, all indices static).
//  - per wave per iter: 8 B-loads + 2 A-DMAs = 10 vmem ops; uniform
//    s_waitcnt vmcnt(10) keeps the newest batch in flight across barriers.
//  - LDS engine traffic per CU-iter drops 176 KB -> 80 KB; LDS 16 KB/block
//    -> 3 blocks/CU (launch_bounds(256,3)) for stall-filling TLP.
//  Numerics: identical bytes for A and B, identical MFMA order (kt, s,
//  hh/hl/lh) -> bit-identical logits vs rounds 0/2/3.
// ---------------------------------------------------------------------------
__global__ __launch_bounds__(256, 3) void router_gemm(const float* __restrict__ X,
                                                      const unsigned short* __restrict__ Ws,
                                                      float* __restrict__ logits) {
    __shared__ float sA[2][BM * BK];   // 2 x 8 KB

    const int tid = threadIdx.x;
    const int lane = tid & 63;
    const int wid = tid >> 6;          // 0..3 = expert group
    const int t0 = blockIdx.x * BM;

    // ---- A staging geometry: 8 DMA instrs/block-iter, wave w does 2 ----
    const int ai0 = wid * 2, ai1 = wid * 2 + 1;
    const int ar0 = 4 * ai0 + (lane >> 4);
    const int ar1 = 4 * ai1 + (lane >> 4);
    const int ak0 = ((lane & 15) ^ (ar0 & 15)) * 4;
    const int ak1 = ((lane & 15) ^ (ar1 & 15)) * 4;
    const float* aSrc0 = X + (size_t)(t0 + ar0) * HIDDEN + ak0;
    const float* aSrc1 = X + (size_t)(t0 + ar1) * HIDDEN + ak1;
    float* aDst0[2] = { &sA[0][ai0 * 256], &sA[1][ai0 * 256] };
    float* aDst1[2] = { &sA[0][ai1 * 256], &sA[1][ai1 * 256] };

    // ---- B source: chunk (k16*8 + wid*2 + hl), 16 B/lane, lane-linear ----
    const unsigned short* bBase = Ws + (size_t)(wid * 2) * 512 + (size_t)lane * 8;

    // ---- compute geometry (A swizzled read) ----
    const int cr = lane & 31;
    const int kb = (lane >> 5) * 2;
    int aoff[4][2];
#pragma unroll
    for (int s = 0; s < 4; ++s) {
        aoff[s][0] = cr * 64 + (((s * 4 + kb + 0) ^ (cr & 15)) * 4);
        aoff[s][1] = cr * 64 + (((s * 4 + kb + 1) ^ (cr & 15)) * 4);
    }

    f32x16 acc;
#pragma unroll
    for (int r = 0; r < 16; ++r) acc[r] = 0.f;

    bf16x8 B0[8], B1[8];   // [s*2 + hl], static indices only

    // B register load for k-iter kt into stage Breg (8 x 16B coalesced loads)
#define LOAD_B(Breg, kt_)                                                        \
    {                                                                            \
        _Pragma("unroll")                                                        \
        for (int s = 0; s < 4; ++s) {                                            \
            Breg[s * 2 + 0] = *(const bf16x8*)(bBase + ((size_t)((kt_) * 4 + s) * 8 + 0) * 512); \
            Breg[s * 2 + 1] = *(const bf16x8*)(bBase + ((size_t)((kt_) * 4 + s) * 8 + 1) * 512); \
        }                                                                        \
    }
    // A DMA for k-iter kt into buffer buf (2 instrs)
#define STAGE_A(buf, kt_)                                                        \
    {                                                                            \
        load_lds_16B(aSrc0 + (kt_) * BK, aDst0[buf]);                            \
        load_lds_16B(aSrc1 + (kt_) * BK, aDst1[buf]);                            \
    }
    // compute one k-iter from sA[buf] + Breg: 4 k16-steps x 3 split terms
#define COMPUTE(buf, Breg)                                                       \
    {                                                                            \
        const float* aBuf = &sA[buf][0];                                         \
        _Pragma("unroll")                                                        \
        for (int s = 0; s < 4; ++s) {                                            \
            const float4 f0 = *(const float4*)(aBuf + aoff[s][0]);               \
            const float4 f1 = *(const float4*)(aBuf + aoff[s][1]);               \
            const bf16x8 ah = pack8_hi(f0, f1);                                  \
            const bf16x8 al = pack8_lo(f0, f1);                                  \
            acc = __builtin_amdgcn_mfma_f32_32x32x16_bf16(ah, Breg[s * 2 + 0], acc, 0, 0, 0); \
            acc = __builtin_amdgcn_mfma_f32_32x32x16_bf16(ah, Breg[s * 2 + 1], acc, 0, 0, 0); \
            acc = __builtin_amdgcn_mfma_f32_32x32x16_bf16(al, Breg[s * 2 + 0], acc, 0, 0, 0); \
        }                                                                        \
    }

    // ---- prologue: batch0 = {A0, B0}, batch1 = {A1, B1}; drain batch0 ----
    STAGE_A(0, 0); LOAD_B(B0, 0);
    __builtin_amdgcn_sched_barrier(0);
    STAGE_A(1, 1); LOAD_B(B1, 1);
    __builtin_amdgcn_sched_barrier(0);
    asm volatile("s_waitcnt vmcnt(10)" ::: "memory");   // batch0 landed
    __builtin_amdgcn_s_barrier();
    asm volatile("" ::: "memory");

#pragma unroll 1
    for (int kt = 0; kt < KIT; kt += 2) {
        // ---------- even half-iter: buffers 0 ----------
        COMPUTE(0, B0);
        __builtin_amdgcn_s_barrier();          // all waves done reading sA[0]
        asm volatile("" ::: "memory");
        {
            int kn = kt + 2; if (kn > KIT - 1) kn = KIT - 1;   // clamped tail
            LOAD_B(B0, kn); STAGE_A(0, kn);
        }
        __builtin_amdgcn_sched_barrier(0);
        asm volatile("s_waitcnt vmcnt(10)" ::: "memory");      // batch kt+1 landed
        __builtin_amdgcn_sched_barrier(0);
        __builtin_amdgcn_s_barrier();
        asm volatile("" ::: "memory");

        // ---------- odd half-iter: buffers 1 ----------
        COMPUTE(1, B1);
        __builtin_amdgcn_s_barrier();          // all waves done reading sA[1]
        asm volatile("" ::: "memory");
        {
            int kn = kt + 3; if (kn > KIT - 1) kn = KIT - 1;
            LOAD_B(B1, kn); STAGE_A(1, kn);
        }
        __builtin_amdgcn_sched_barrier(0);
        asm volatile("s_waitcnt vmcnt(10)" ::: "memory");      // batch kt+2 landed
        __builtin_amdgcn_sched_barrier(0);
        __builtin_amdgcn_s_barrier();
        asm volatile("" ::: "memory");
    }
    asm volatile("s_waitcnt vmcnt(0)" ::: "memory");    // drain tail issues

#undef LOAD_B
#undef STAGE_A
#undef COMPUTE

    // C/D: col=lane&31, row=(reg&3)+8*(reg>>2)+4*(lane>>5)  (r6-verified)
    const int e = wid * 32 + (lane & 31);
    const int rbase = 4 * (lane >> 5);
#pragma unroll
    for (int reg = 0; reg < 16; ++reg) {
        const int row = (reg & 3) + 8 * (reg >> 2) + rbase;
        logits[(size_t)(t0 + row) * NEXP + e] = acc[reg];
    }
}

// ---------------------------------------------------------------------------
// K2: fused select+refine. UNCHANGED.
// ---------------------------------------------------------------------------
__global__ __launch_bounds__(256) void router_topk(const float* __restrict__ logits,
                                                   const float* __restrict__ X,
                                                   const float* __restrict__ W,
                                                   float* __restrict__ top_vals,
                                                   float* __restrict__ top_idx) {
    const int lane = threadIdx.x & 63;
    const int t = blockIdx.x * 4 + (threadIdx.x >> 6);
    const float* lrow = logits + (size_t)t * NEXP;
    const float l0 = lrow[lane];
    const float l1 = lrow[lane + 64];
    bool r0 = false, r1 = false;
    float vals[NCAND]; int idxs[NCAND];

#pragma unroll
    for (int it = 0; it < TOPK + 1; ++it) {
        const float c0 = r0 ? -FLT_MAX : l0;
        const float c1 = r1 ? -FLT_MAX : l1;
        float v; int id;
        if (c1 > c0) { v = c1; id = lane + 64; }
        else         { v = c0; id = lane; }
#pragma unroll
        for (int off = 1; off < 64; off <<= 1) {
            const float ov = __shfl_xor(v, off);
            const int   oi = __shfl_xor(id, off);
            if (ov > v || (ov == v && oi < id)) { v = ov; id = oi; }
        }
        vals[it] = v; idxs[it] = id;
        if (id == lane) r0 = true;
        else if (id == lane + 64) r1 = true;
    }

    float ming = FLT_MAX;
#pragma unroll
    for (int i = 0; i < TOPK; ++i) ming = fminf(ming, vals[i] - vals[i + 1]);

    if (ming >= DELTA) {
        if (lane == 0) {
            const float m = vals[0];
            float ex[TOPK], s = 0.f;
#pragma unroll
            for (int i = 0; i < TOPK; ++i) { ex[i] = expf(vals[i] - m); s += ex[i]; }
            const float inv = 1.f / s;
#pragma unroll
            for (int i = 0; i < TOPK; ++i) {
                top_vals[(size_t)t * TOPK + i] = ex[i] * inv;
                top_idx[(size_t)t * TOPK + i] = (float)idxs[i];
            }
        }
        return;
    }

    // ---- slow path (wave-uniform): extend candidates to NCAND
#pragma unroll
    for (int it = TOPK + 1; it < NCAND; ++it) {
        const float c0 = r0 ? -FLT_MAX : l0;
        const float c1 = r1 ? -FLT_MAX : l1;
        float v; int id;
        if (c1 > c0) { v = c1; id = lane + 64; }
        else         { v = c0; id = lane; }
#pragma unroll
        for (int off = 1; off < 64; off <<= 1) {
            const float ov = __shfl_xor(v, off);
            const int   oi = __shfl_xor(id, off);
            if (ov > v || (ov == v && oi < id)) { v = ov; id = oi; }
        }
        vals[it] = v; idxs[it] = id;
        if (id == lane) r0 = true;
        else if (id == lane + 64) r1 = true;
    }

    // exact fp64 recompute of the NCAND candidate logits (coalesced)
    const float* xr = X + (size_t)t * HIDDEN;
    double xd[32];
#pragma unroll
    for (int j = 0; j < 8; ++j) {
        const float4 v = *(const float4*)(xr + j * 256 + lane * 4);
        xd[j * 4 + 0] = (double)v.x; xd[j * 4 + 1] = (double)v.y;
        xd[j * 4 + 2] = (double)v.z; xd[j * 4 + 3] = (double)v.w;
    }
    double acc[NCAND];
#pragma unroll
    for (int c = 0; c < NCAND; ++c) {
        const float* wr = W + (size_t)idxs[c] * HIDDEN;
        double a0 = 0.0, a1 = 0.0;
#pragma unroll
        for (int j = 0; j < 8; ++j) {
            const float4 w = *(const float4*)(wr + j * 256 + lane * 4);
            a0 = fma((double)w.x, xd[j * 4 + 0], a0);
            a1 = fma((double)w.y, xd[j * 4 + 1], a1);
            a0 = fma((double)w.z, xd[j * 4 + 2], a0);
            a1 = fma((double)w.w, xd[j * 4 + 3], a1);
        }
        acc[c] = a0 + a1;
    }
#pragma unroll
    for (int c = 0; c < NCAND; ++c)
#pragma unroll
        for (int off = 1; off < 64; off <<= 1)
            acc[c] += __shfl_xor(acc[c], off);

    int rank[NCAND];
#pragma unroll
    for (int c = 0; c < NCAND; ++c) {
        int r = 0;
#pragma unroll
        for (int m = 0; m < NCAND; ++m)
            if (acc[m] > acc[c] || (acc[m] == acc[c] && idxs[m] < idxs[c])) ++r;
        rank[c] = r;
    }
    double vmax = acc[0];
#pragma unroll
    for (int c = 0; c < NCAND; ++c) if (rank[c] == 0) vmax = acc[c];
    float ex[NCAND], s = 0.f;
#pragma unroll
    for (int c = 0; c < NCAND; ++c) {
        ex[c] = (rank[c] < TOPK) ? expf((float)(acc[c] - vmax)) : 0.f;
        s += ex[c];
    }
    const float inv = 1.f / s;
    if (lane == 0) {
#pragma unroll
        for (int c = 0; c < NCAND; ++c)
            if (rank[c] < TOPK) {
                top_vals[(size_t)t * TOPK + rank[c]] = ex[c] * inv;
                top_idx[(size_t)t * TOPK + rank[c]] = (float)idxs[c];
            }
    }
}

extern "C" void kernel_launch(void* const* d_in, const int* in_sizes, int n_in,
                              void* d_out, int out_size, void* d_ws, size_t ws_size,
                              hipStream_t stream) {
    const float* X = (const float*)d_in[0];   // [16384, 2048] f32
    const float* W = (const float*)d_in[1];   // [128, 2048] f32
    float* logits = (float*)d_out;                          // [16384,128]
    float* tvals  = logits + (size_t)TOKENS * NEXP;         // [16384,8]
    float* tidx   = tvals + (size_t)TOKENS * TOPK;          // [16384,8]

    unsigned short* Wsplit = (unsigned short*)d_ws;         // 1 MB

    presplit_w<<<256, 256, 0, stream>>>(W, Wsplit);
    router_gemm<<<TOKENS / BM, 256, 0, stream>>>(X, Wsplit, logits);
    router_topk<<<TOKENS / 4, 256, 0, stream>>>(logits, X, W, tvals, tidx);
}